// Round 5
// baseline (234.610 us; speedup 1.0000x reference)
//
#include <hip/hip_runtime.h>
#include <stdint.h>

// MomentumLIF: x[N,T,D] f32 -> spikes[N,T,D] f32 (0/1)
//   v_t = mom*v + x_t - lamb*u ; u_t = 0.5*u + v_t ; s = (u>=1); u *= (1-s)
//
// R5: R1-R4 (all source-level pipelines) pinned at ~80us = 64 x ~3000cyc =
// one memory round-trip per timestep: the scheduler sinks every load to its
// use (R3: VGPR=16 proves the 8-deep buffer collapsed), so each wave runs a
// serial 64-load latency chain and kernel time == that chain. Fix: take the
// waitcnt schedule away from the compiler. Loads are volatile inline-asm
// global_load_dword (compiler has no VMEM tracking for them -> inserts no
// waits); s_waitcnt vmcnt(15) is hand-placed with a "+v" data tie to the
// consumed slot -> guaranteed 16-deep pipeline (4 exposed round-trips total).
// Spikes are bit-packed into 2 VGPRs; all 64 stores go out as a pure burst
// at the end, keeping stores out of the load vmcnt stream.

#define N_ 64
#define T_ 64
#define D_ 8192
#define PF 16   // hand-held load pipeline depth

__global__ __launch_bounds__(256) void MomentumLIF_kernel(
    const float* __restrict__ x,
    const float* __restrict__ momp,
    const float* __restrict__ lambp,
    float* __restrict__ out)
{
    // Match numpy f32 semantics exactly: no FMA contraction anywhere.
#pragma clang fp contract(off)
    float mom  = momp[0];
    float lamb = lambp[0];
    const float decay = 0.5f;   // 1 - 1/TAU, exact

    // Force mom/lamb materialized (and any compiler-tracked loads drained by
    // its own waitcnts) BEFORE our hand-counted loads start, so our vmcnt
    // arithmetic sees only our own loads.
    asm volatile("" : "+s"(mom), "+s"(lamb));

    const int tid = blockIdx.x * blockDim.x + threadIdx.x;  // [0, N*D)
    const int n = tid >> 13;         // / D_
    const int d = tid & (D_ - 1);

    const float* xp = x   + (size_t)n * T_ * D_ + d;
    float*       op = out + (size_t)n * T_ * D_ + d;

    float xs[PF];

    // Prologue: issue PF loads (volatile asm -> order pinned, no compiler waits).
#pragma unroll
    for (int i = 0; i < PF; ++i) {
        const float* a = xp + (size_t)i * D_;
        asm volatile("global_load_dword %0, %1, off" : "=v"(xs[i]) : "v"(a));
    }

    float u = 0.f, v = 0.f;
    uint32_t blo = 0u, bhi = 0u;   // bit-packed spikes, t<32 / t>=32

    // Main loop: outstanding loads == 16 at every wait; vmcnt(15) retires
    // exactly the oldest (slot t), keeping 15 younger loads in flight.
#pragma unroll
    for (int t = 0; t < T_ - PF; ++t) {
        const int slot = t & (PF - 1);
        asm volatile("s_waitcnt vmcnt(15)" : "+v"(xs[slot]));
        const float xt = xs[slot];
        const float* a = xp + (size_t)(t + PF) * D_;
        asm volatile("global_load_dword %0, %1, off" : "=v"(xs[slot]) : "v"(a));

        float t1 = mom * v;            // separately rounded, matches numpy
        float t2 = lamb * u;
        v = (t1 + xt) - t2;
        u = decay * u + v;
        const bool sp = (u >= 1.0f);
        if (t < 32) blo |= ((uint32_t)sp) << t;
        else        bhi |= ((uint32_t)sp) << (t - 32);
        u = sp ? 0.0f : u;             // u*(1-s) is exactly this select
    }

    // Epilogue: drain the last 16 loads, tie ALL slots so no consume hoists
    // above the wait.
    asm volatile("s_waitcnt vmcnt(0)"
                 : "+v"(xs[0]),  "+v"(xs[1]),  "+v"(xs[2]),  "+v"(xs[3]),
                   "+v"(xs[4]),  "+v"(xs[5]),  "+v"(xs[6]),  "+v"(xs[7]),
                   "+v"(xs[8]),  "+v"(xs[9]),  "+v"(xs[10]), "+v"(xs[11]),
                   "+v"(xs[12]), "+v"(xs[13]), "+v"(xs[14]), "+v"(xs[15]));

#pragma unroll
    for (int t = T_ - PF; t < T_; ++t) {
        const float xt = xs[t & (PF - 1)];
        float t1 = mom * v;
        float t2 = lamb * u;
        v = (t1 + xt) - t2;
        u = decay * u + v;
        const bool sp = (u >= 1.0f);
        if (t < 32) blo |= ((uint32_t)sp) << t;
        else        bhi |= ((uint32_t)sp) << (t - 32);
        u = sp ? 0.0f : u;
    }

    // Store burst: 64 independent dword stores, nothing to wait on; the HW
    // pipelines them back-to-back (BW-bound).
#pragma unroll
    for (int t = 0; t < T_; ++t) {
        const uint32_t bit = ((t < 32 ? blo : bhi) >> (t & 31)) & 1u;
        op[(size_t)t * D_] = bit ? 1.0f : 0.0f;
    }
}

extern "C" void kernel_launch(void* const* d_in, const int* in_sizes, int n_in,
                              void* d_out, int out_size, void* d_ws, size_t ws_size,
                              hipStream_t stream) {
    const float* x    = (const float*)d_in[0];
    const float* momp = (const float*)d_in[1];
    const float* lamb = (const float*)d_in[2];
    float* out = (float*)d_out;

    const int threads = N_ * D_;         // 524288 chains, 1 per thread
    dim3 block(256);
    dim3 grid(threads / 256);            // 2048 blocks -> 8 blocks/CU
    hipLaunchKernelGGL(MomentumLIF_kernel, grid, block, 0, stream,
                       x, momp, lamb, out);
}

// Round 6
// 233.703 us; speedup vs baseline: 1.0039x; 1.0039x over previous
//
#include <hip/hip_runtime.h>
#include <stdint.h>

// MomentumLIF: x[N,T,D] f32 -> spikes[N,T,D] f32 (0/1)
//   v_t = mom*v + x_t - lamb*u ; u_t = 0.5*u + v_t ; s = (u>=1); u *= (1-s)
//
// R6: R1-R5 proved the wall (~80us, 3.3 TB/s logical) is invariant to MLP
// depth (4..16), occupancy (18..68%), load width, and store placement --
// even a verified 16-deep asm pipeline (R5: VGPR=40) changed nothing. The
// remaining suspect is the VGPR-return load path's per-CU service rate.
// This round swaps the read mechanism: global_load_lds (LDS-DMA, no VGPR
// return -- the m93->m97 lever). Each wave stages ONLY its own 64 chains
// (lane-scatter == consumption order), so producer==consumer wave and NO
// __syncthreads exists; the hazard is handled by hand-placed literal
// s_waitcnt vmcnt(8/0) (LDS-DMA completion counts in vmcnt). 16-slot LDS
// ring (16KB/block, 8 blocks/CU), chunked 8-consume/8-refill. Spikes
// bit-packed into 2 VGPRs, stored as a pure burst at the end.

#define N_ 64
#define T_ 64
#define D_ 8192
#define RS 16     // LDS ring slots (timesteps resident)
#define CHK 8     // consume/refill chunk

typedef __attribute__((address_space(1))) uint32_t* gptr_t;
typedef __attribute__((address_space(3))) uint32_t* lptr_t;

__global__ __launch_bounds__(256) void MomentumLIF_kernel(
    const float* __restrict__ x,
    const float* __restrict__ momp,
    const float* __restrict__ lambp,
    float* __restrict__ out)
{
    // Match numpy f32 semantics exactly: no FMA contraction anywhere.
#pragma clang fp contract(off)
    __shared__ uint32_t smem[RS * 256];

    const float mom  = momp[0];
    const float lamb = lambp[0];
    const float decay = 0.5f;   // 1 - 1/TAU, exact

    const int tid = threadIdx.x;
    const int blk = blockIdx.x;          // 2048 blocks
    const int n   = blk >> 5;            // 32 d-chunks per n
    const int d   = ((blk & 31) << 8) + tid;   // this thread's chain
    const int wbase = tid & 192;         // wave-uniform LDS sub-base (wave*64 lanes)

    const uint32_t* xrow = reinterpret_cast<const uint32_t*>(x)
                         + (size_t)n * T_ * D_ + d;
    float* op = out + (size_t)n * T_ * D_ + d;

    // Drain any compiler-tracked vmem so our vmcnt arithmetic sees only
    // our own staging loads.
    asm volatile("s_waitcnt vmcnt(0)" ::: "memory");

    // Stage timestep t_: lane l of wave w DMAs x[n, t_, dbase+64w+l] into
    // smem[slot*256 + 64w + l]. LDS dest is wave-uniform base + lane*4,
    // which exactly matches each lane's consumption address.
#define STAGE(t_) __builtin_amdgcn_global_load_lds(                       \
        (gptr_t)(xrow + (size_t)(t_) * D_),                               \
        (lptr_t)(&smem[(((t_) & (RS - 1)) << 8) + wbase]), 4, 0, 0)

    // Prologue: fill the 16-slot ring.
#pragma unroll
    for (int t = 0; t < RS; ++t) STAGE(t);

    float u = 0.f, v = 0.f;
    uint32_t blo = 0u, bhi = 0u;   // bit-packed spikes, t<32 / t>=32

#pragma unroll
    for (int c = 0; c < T_ / CHK; ++c) {
        // Chunks 0..6: oldest 8 stages done, 8 younger stay in flight.
        // Chunk 7: drain everything.
        if (c < 7) asm volatile("s_waitcnt vmcnt(8)" ::: "memory");
        else       asm volatile("s_waitcnt vmcnt(0)" ::: "memory");

#pragma unroll
        for (int i = 0; i < CHK; ++i) {
            const int t = c * CHK + i;
            const float xt =
                __uint_as_float(smem[((t & (RS - 1)) << 8) + tid]);

            float t1 = mom * v;        // separately rounded, matches numpy
            float t2 = lamb * u;
            v = (t1 + xt) - t2;
            u = decay * u + v;
            const bool sp = (u >= 1.0f);
            if (t < 32) blo |= ((uint32_t)sp) << t;
            else        bhi |= ((uint32_t)sp) << (t - 32);
            u = sp ? 0.0f : u;         // u*(1-s) is exactly this select
        }

        // Refill the slots just consumed (slots (c*8..c*8+7) & 15).
        if (c < 6) {
#pragma unroll
            for (int i = 0; i < CHK; ++i) STAGE(RS + c * CHK + i);
        }
    }
#undef STAGE

    // Store burst: 64 independent dword stores, pipelined back-to-back.
#pragma unroll
    for (int t = 0; t < T_; ++t) {
        const uint32_t bit = ((t < 32 ? blo : bhi) >> (t & 31)) & 1u;
        op[(size_t)t * D_] = bit ? 1.0f : 0.0f;
    }
}

extern "C" void kernel_launch(void* const* d_in, const int* in_sizes, int n_in,
                              void* d_out, int out_size, void* d_ws, size_t ws_size,
                              hipStream_t stream) {
    const float* x    = (const float*)d_in[0];
    const float* momp = (const float*)d_in[1];
    const float* lamb = (const float*)d_in[2];
    float* out = (float*)d_out;

    const int threads = N_ * D_;         // 524288 chains, 1 per thread
    dim3 block(256);
    dim3 grid(threads / 256);            // 2048 blocks -> 8 blocks/CU
    hipLaunchKernelGGL(MomentumLIF_kernel, grid, block, 0, stream,
                       x, momp, lamb, out);
}

// Round 8
// 231.033 us; speedup vs baseline: 1.0155x; 1.0116x over previous
//
#include <hip/hip_runtime.h>
#include <stdint.h>

// MomentumLIF: x[N,T,D] f32 -> spikes[N,T,D] f32 (0/1)
//   v_t = mom*v + x_t - lamb*u ; u_t = 0.5*u + v_t ; s = (u>=1); u *= (1-s)
//
// R8 (= R7 with the nontemporal-store type fixed): phase-split into two
// stream-pure dispatches to isolate read vs write paths.
//   A: read x (16-deep asm load pipeline), run recurrence, pack 64 spike
//      bits/chain into uint2 -> d_ws (4 MB). Pure-read + negligible write.
//   B: expand bits -> out as fully-contiguous float4 nontemporal stores.
//      Pure-write (ws reads 4 MB, L2-resident). Structurally == the 6.85
//      TB/s harness fill.
// Diagnostic either way: A's isolated duration pins the read path.

#define N_ 64
#define T_ 64
#define D_ 8192
#define PF 16   // kernel A load pipeline depth

typedef __attribute__((ext_vector_type(4))) float f32x4;  // clang-native

// ---------------- Kernel A: recurrence + bit-pack ----------------
__global__ __launch_bounds__(256) void lif_compute_pack(
    const float* __restrict__ x,
    const float* __restrict__ momp,
    const float* __restrict__ lambp,
    uint2* __restrict__ ws)
{
    // Match numpy f32 semantics exactly: no FMA contraction anywhere.
#pragma clang fp contract(off)
    float mom  = momp[0];
    float lamb = lambp[0];
    const float decay = 0.5f;   // 1 - 1/TAU, exact

    // Pin scalars and drain compiler-tracked vmem so our vmcnt arithmetic
    // sees only our own loads.
    asm volatile("" : "+s"(mom), "+s"(lamb));

    const int tid = blockIdx.x * blockDim.x + threadIdx.x;  // chain id
    const int n = tid >> 13;
    const int d = tid & (D_ - 1);
    const float* xp = x + (size_t)n * T_ * D_ + d;

    asm volatile("s_waitcnt vmcnt(0)" ::: "memory");

    float xs[PF];
#pragma unroll
    for (int i = 0; i < PF; ++i) {
        const float* a = xp + (size_t)i * D_;
        asm volatile("global_load_dword %0, %1, off" : "=v"(xs[i]) : "v"(a));
    }

    float u = 0.f, v = 0.f;
    uint32_t blo = 0u, bhi = 0u;   // packed spikes, t<32 / t>=32

    // 16-deep pipeline (R5-verified to survive into the final schedule).
#pragma unroll
    for (int t = 0; t < T_ - PF; ++t) {
        const int slot = t & (PF - 1);
        asm volatile("s_waitcnt vmcnt(15)" : "+v"(xs[slot]));
        const float xt = xs[slot];
        const float* a = xp + (size_t)(t + PF) * D_;
        asm volatile("global_load_dword %0, %1, off" : "=v"(xs[slot]) : "v"(a));

        float t1 = mom * v;            // separately rounded, matches numpy
        float t2 = lamb * u;
        v = (t1 + xt) - t2;
        u = decay * u + v;
        const bool sp = (u >= 1.0f);
        if (t < 32) blo |= ((uint32_t)sp) << t;
        else        bhi |= ((uint32_t)sp) << (t - 32);
        u = sp ? 0.0f : u;             // u*(1-s) is exactly this select
    }

    asm volatile("s_waitcnt vmcnt(0)"
                 : "+v"(xs[0]),  "+v"(xs[1]),  "+v"(xs[2]),  "+v"(xs[3]),
                   "+v"(xs[4]),  "+v"(xs[5]),  "+v"(xs[6]),  "+v"(xs[7]),
                   "+v"(xs[8]),  "+v"(xs[9]),  "+v"(xs[10]), "+v"(xs[11]),
                   "+v"(xs[12]), "+v"(xs[13]), "+v"(xs[14]), "+v"(xs[15]));

#pragma unroll
    for (int t = T_ - PF; t < T_; ++t) {
        const float xt = xs[t & (PF - 1)];
        float t1 = mom * v;
        float t2 = lamb * u;
        v = (t1 + xt) - t2;
        u = decay * u + v;
        const bool sp = (u >= 1.0f);
        if (t < 32) blo |= ((uint32_t)sp) << t;
        else        bhi |= ((uint32_t)sp) << (t - 32);
        u = sp ? 0.0f : u;
    }

    // 8 B per chain, contiguous dwordx2 per wave. 4 MB total.
    ws[tid] = make_uint2(blo, bhi);
}

// ---------------- Kernel B: bit -> float expand, pure-write ----------------
__global__ __launch_bounds__(256) void lif_expand(
    const uint2* __restrict__ ws,
    float* __restrict__ out)
{
    const int g = blockIdx.x * blockDim.x + threadIdx.x;  // one float4 of out
    const size_t e = (size_t)g << 2;          // element index, multiple of 4
    const int nt = (int)(e >> 13);            // n*T + t   (row = D elements)
    const int t  = nt & (T_ - 1);
    const int n  = nt >> 6;                   // / T_
    const int d  = (int)(e & (D_ - 1));
    const int chain = (n << 13) + d;          // n*D + d

    // 4 consecutive chains' packed words: 32 B contiguous, L2-resident
    // (ws is 4 MB, read 32x over the whole grid).
    const uint2 w0 = ws[chain + 0];
    const uint2 w1 = ws[chain + 1];
    const uint2 w2 = ws[chain + 2];
    const uint2 w3 = ws[chain + 3];

    const int  sh = t & 31;
    const bool hi = (t >= 32);

    f32x4 o;
    o.x = (((hi ? w0.y : w0.x) >> sh) & 1u) ? 1.0f : 0.0f;
    o.y = (((hi ? w1.y : w1.x) >> sh) & 1u) ? 1.0f : 0.0f;
    o.z = (((hi ? w2.y : w2.x) >> sh) & 1u) ? 1.0f : 0.0f;
    o.w = (((hi ? w3.y : w3.x) >> sh) & 1u) ? 1.0f : 0.0f;

    // Fully contiguous chip-wide write stream, 16 B/lane, nontemporal.
    __builtin_nontemporal_store(o, reinterpret_cast<f32x4*>(out) + g);
}

extern "C" void kernel_launch(void* const* d_in, const int* in_sizes, int n_in,
                              void* d_out, int out_size, void* d_ws, size_t ws_size,
                              hipStream_t stream) {
    const float* x    = (const float*)d_in[0];
    const float* momp = (const float*)d_in[1];
    const float* lamb = (const float*)d_in[2];
    float* out = (float*)d_out;
    uint2* ws  = (uint2*)d_ws;                // 524288 * 8 B = 4 MB

    // A: one thread per chain.
    {
        dim3 block(256);
        dim3 grid((N_ * D_) / 256);           // 2048 blocks
        hipLaunchKernelGGL(lif_compute_pack, grid, block, 0, stream,
                           x, momp, lamb, ws);
    }
    // B: one thread per float4 of out.
    {
        dim3 block(256);
        dim3 grid((N_ * T_ * D_ / 4) / 256);  // 32768 blocks
        hipLaunchKernelGGL(lif_expand, grid, block, 0, stream, ws, out);
    }
}